// Round 1
// 1289.072 us; speedup vs baseline: 1.0062x; 1.0062x over previous
//
#include <hip/hip_runtime.h>

// MultiMarginLoss forward, p=1, margin=1.0, mean reduction.
// input: [B, C] fp32; target: [B] int32; out: scalar fp32.
//
// loss_row = sum_{j != t} max(0, 1 - (x[t] - x[j]))
//          = (sum_{all j} max(0, (1 - x[t]) + x[j])) - 1.0   // target term == 1.0 exactly
// out = mean over rows.
//
// v2: single fused main kernel. Each block owns 8 rows; the per-row
// threshold gather (2 dependent scattered loads) is done by threads 0..7
// into LDS at block start. The streaming loop walks column chunks and
// issues 8 INDEPENDENT float4 loads (one per row) before consuming any —
// 8 KB in flight per wave vs ~1 KB in the serial-row version, which was
// latency-bound at ~1.7 TB/s effective. Target: >5 TB/s read.

#define ROWS_PER_BLOCK 8
#define BLOCK 256

__global__ void mml_init_kernel(float* __restrict__ out) {
    if (threadIdx.x == 0) out[0] = 0.0f;
}

__global__ __launch_bounds__(BLOCK) void mml_main_kernel(const float* __restrict__ input,
                                                         const int* __restrict__ target,
                                                         float* __restrict__ out,
                                                         int B, int C, float inv_B) {
    const int r0 = blockIdx.x * ROWS_PER_BLOCK;
    const int nvalid = (B - r0 < ROWS_PER_BLOCK) ? (B - r0) : ROWS_PER_BLOCK;

    // ---- fused threshold gather: th[row] = 1 - x[row, t_row] ----
    __shared__ float s_th[ROWS_PER_BLOCK];
    if (threadIdx.x < ROWS_PER_BLOCK) {
        const int row = r0 + threadIdx.x;
        float th = -INFINITY;  // rows past B: th + x = -inf -> fmax(0, .) = 0
        if (row < B) {
            const int t = target[row];
            th = 1.0f - input[(size_t)row * (size_t)C + t];
        }
        s_th[threadIdx.x] = th;
    }
    __syncthreads();

    float th[ROWS_PER_BLOCK];
    const float4* __restrict__ rp[ROWS_PER_BLOCK];
    #pragma unroll
    for (int r = 0; r < ROWS_PER_BLOCK; ++r) {
        th[r] = s_th[r];
        const int row = (r0 + r < B) ? (r0 + r) : r0;  // clamped; masked by th = -inf
        rp[r] = (const float4*)(input + (size_t)row * (size_t)C);
    }

    const int n4 = C >> 2;
    float acc[ROWS_PER_BLOCK];
    #pragma unroll
    for (int r = 0; r < ROWS_PER_BLOCK; ++r) acc[r] = 0.0f;

    // ---- streaming loop: 8 independent loads in flight per iteration ----
    for (int i = threadIdx.x; i < n4; i += BLOCK) {
        float4 v[ROWS_PER_BLOCK];
        #pragma unroll
        for (int r = 0; r < ROWS_PER_BLOCK; ++r) v[r] = rp[r][i];
        #pragma unroll
        for (int r = 0; r < ROWS_PER_BLOCK; ++r) {
            acc[r] += fmaxf(0.0f, th[r] + v[r].x);
            acc[r] += fmaxf(0.0f, th[r] + v[r].y);
            acc[r] += fmaxf(0.0f, th[r] + v[r].z);
            acc[r] += fmaxf(0.0f, th[r] + v[r].w);
        }
    }

    // tail for C % 4 != 0 (empty for C = 32000)
    for (int i = (n4 << 2) + threadIdx.x; i < C; i += BLOCK) {
        #pragma unroll
        for (int r = 0; r < ROWS_PER_BLOCK; ++r) {
            const float* rowp = (const float*)rp[r];
            acc[r] += fmaxf(0.0f, th[r] + rowp[i]);
        }
    }

    // ---- block reduction, one atomic per block ----
    float tot = 0.0f;
    #pragma unroll
    for (int r = 0; r < ROWS_PER_BLOCK; ++r) tot += acc[r];

    #pragma unroll
    for (int off = 32; off > 0; off >>= 1)
        tot += __shfl_down(tot, off, 64);

    __shared__ float s_part[BLOCK / 64];
    const int lane = threadIdx.x & 63;
    const int wave = threadIdx.x >> 6;
    if (lane == 0) s_part[wave] = tot;
    __syncthreads();

    if (threadIdx.x == 0) {
        float sum = 0.0f;
        #pragma unroll
        for (int w = 0; w < BLOCK / 64; ++w) sum += s_part[w];
        sum -= (float)nvalid;          // remove target-column hinge (== 1.0) per valid row
        atomicAdd(out, sum * inv_B);   // 1024 atomics to one address
    }
}

extern "C" void kernel_launch(void* const* d_in, const int* in_sizes, int n_in,
                              void* d_out, int out_size, void* d_ws, size_t ws_size,
                              hipStream_t stream) {
    const float* input = (const float*)d_in[0];
    const int* target = (const int*)d_in[1];
    float* out = (float*)d_out;

    const int B = in_sizes[1];                // 8192
    const int C = in_sizes[0] / in_sizes[1];  // 32000

    mml_init_kernel<<<1, 64, 0, stream>>>(out);

    const int grid = (B + ROWS_PER_BLOCK - 1) / ROWS_PER_BLOCK;  // 1024
    mml_main_kernel<<<grid, BLOCK, 0, stream>>>(input, target, out, B, C, 1.0f / (float)B);
}